// Round 1
// baseline (326.120 us; speedup 1.0000x reference)
//
#include <hip/hip_runtime.h>

#define NB 8
#define CH 256
#define NT 2304
#define ATTN_SCALE 0.17677669529663687f
#define LN_EPS 1e-6f

typedef __attribute__((ext_vector_type(8))) short short8;
typedef __attribute__((ext_vector_type(4))) float f32x4;
typedef __attribute__((ext_vector_type(4))) unsigned short ushort4v;
typedef __attribute__((ext_vector_type(8))) unsigned short ushort8v;
typedef __attribute__((ext_vector_type(4))) float float4v;

__device__ __forceinline__ unsigned short f2bf(float f) {
  unsigned int u = __float_as_uint(f);
  u += 0x7fffu + ((u >> 16) & 1u);
  return (unsigned short)(u >> 16);
}

__device__ __forceinline__ void gload_lds16(const void* g, void* l) {
  __builtin_amdgcn_global_load_lds(
      (const __attribute__((address_space(1))) unsigned int*)g,
      (__attribute__((address_space(3))) unsigned int*)l, 16, 0, 0);
}

// ---------------- weight fp32 -> bf16 convert ----------------
__global__ __launch_bounds__(256) void wconv_kernel(
    const float* __restrict__ wq, const float* __restrict__ wk,
    const float* __restrict__ wv, const float* __restrict__ wp,
    unsigned short* __restrict__ out) {
  int z = blockIdx.y;
  const float* src = (z == 0) ? wq : (z == 1) ? wk : (z == 2) ? wv : wp;
  unsigned short* dst = out + z * 65536;
  int i = (blockIdx.x * 256 + threadIdx.x) * 4;
  float4v v = *(const float4v*)(src + i);
  ushort4v r;
  r[0] = f2bf(v[0]); r[1] = f2bf(v[1]); r[2] = f2bf(v[2]); r[3] = f2bf(v[3]);
  *(ushort4v*)(dst + i) = r;
}

// ---------------- channel LayerNorm + transpose to [B,N,C] bf16 ----------------
__global__ __launch_bounds__(256) void ln_kernel(
    const float* __restrict__ x, const float* __restrict__ w,
    const float* __restrict__ bias, unsigned short* __restrict__ out) {
  int n = blockIdx.x * 256 + threadIdx.x;
  int b = blockIdx.y;
  const float* xp = x + (size_t)b * CH * NT + n;
  float sum = 0.f, ss = 0.f;
#pragma unroll 4
  for (int c = 0; c < CH; ++c) {
    float v = xp[(size_t)c * NT];
    sum += v; ss += v * v;
  }
  float u = sum * (1.0f / CH);
  float var = ss * (1.0f / CH) - u * u;
  float rstd = rsqrtf(var + LN_EPS);
  unsigned short* op = out + ((size_t)b * NT + n) * CH;
  for (int c0 = 0; c0 < CH; c0 += 8) {
    ushort8v pk;
#pragma unroll
    for (int j = 0; j < 8; ++j) {
      float v = xp[(size_t)(c0 + j) * NT];
      float xn = (v - u) * rstd * w[c0 + j] + bias[c0 + j];
      pk[j] = f2bf(xn);
    }
    *(ushort8v*)(op + c0) = pk;
  }
}

// ---------------- QKV projection GEMM (128x128, BK=64, 4 waves) ----------------
// A: [NT, CH] bf16 row-major.  W: [CH, CH] bf16 row-major (out-ch major) == B^T.
// pz 0 -> q [B,N,C]; pz 1 -> k [B,N,C]; pz 2 -> v transposed [B,C,N].
__global__ __launch_bounds__(256) void proj_kernel(
    const unsigned short* __restrict__ xq, const unsigned short* __restrict__ xkv,
    const unsigned short* __restrict__ wbf,
    const float* __restrict__ bq, const float* __restrict__ bk,
    const float* __restrict__ bv,
    unsigned short* __restrict__ q, unsigned short* __restrict__ k,
    unsigned short* __restrict__ vt) {
  __shared__ char As[16384];
  __shared__ char Bs[16384];
  int tid = threadIdx.x;
  int lane = tid & 63, wid = tid >> 6;
  int z = blockIdx.z;
  int b = z / 3, pz = z - b * 3;
  const unsigned short* A = ((pz == 0) ? xq : xkv) + (size_t)b * NT * CH;
  const unsigned short* W = wbf + pz * 65536;
  const float* bias = (pz == 0) ? bq : (pz == 1) ? bk : bv;
  int m0 = blockIdx.x * 128;
  int c0 = blockIdx.y * 128;
  int wr = wid >> 1, wc = wid & 1;

  f32x4 zero4 = {0.f, 0.f, 0.f, 0.f};
  f32x4 acc[4][4];
#pragma unroll
  for (int i = 0; i < 4; ++i)
#pragma unroll
    for (int j = 0; j < 4; ++j) acc[i][j] = zero4;

  for (int kt = 0; kt < 4; ++kt) {
#pragma unroll
    for (int it = 0; it < 4; ++it) {
      int li = it * 256 + tid;
      int X = li * 16;
      int row = X >> 7;
      int colb = (X & 127) ^ ((row & 7) << 4);
      gload_lds16((const char*)A + ((size_t)(m0 + row) * CH + kt * 64) * 2 + colb,
                  As + it * 4096 + wid * 1024);
      gload_lds16((const char*)W + ((size_t)(c0 + row) * CH + kt * 64) * 2 + colb,
                  Bs + it * 4096 + wid * 1024);
    }
    __syncthreads();
#pragma unroll
    for (int kk = 0; kk < 2; ++kk) {
      int cb = kk * 64 + ((lane >> 4) << 4);
      short8 af[4], bf[4];
#pragma unroll
      for (int mi = 0; mi < 4; ++mi) {
        int row = wr * 64 + mi * 16 + (lane & 15);
        af[mi] = *(const short8*)(As + row * 128 + (cb ^ ((row & 7) << 4)));
      }
#pragma unroll
      for (int ni = 0; ni < 4; ++ni) {
        int row = wc * 64 + ni * 16 + (lane & 15);
        bf[ni] = *(const short8*)(Bs + row * 128 + (cb ^ ((row & 7) << 4)));
      }
#pragma unroll
      for (int mi = 0; mi < 4; ++mi)
#pragma unroll
        for (int ni = 0; ni < 4; ++ni)
          acc[mi][ni] = __builtin_amdgcn_mfma_f32_16x16x32_bf16(
              af[mi], bf[ni], acc[mi][ni], 0, 0, 0);
    }
    __syncthreads();
  }

  int colbase = c0 + wc * 64;
  int rowbase = m0 + wr * 64;
  if (pz < 2) {
    unsigned short* dst = ((pz == 0) ? q : k) + (size_t)b * NT * CH;
#pragma unroll
    for (int mi = 0; mi < 4; ++mi)
#pragma unroll
      for (int ni = 0; ni < 4; ++ni) {
        int col = colbase + ni * 16 + (lane & 15);
        float bb = bias[col];
        int row0 = rowbase + mi * 16 + ((lane >> 4) << 2);
#pragma unroll
        for (int r = 0; r < 4; ++r)
          dst[(size_t)(row0 + r) * CH + col] = f2bf(acc[mi][ni][r] + bb);
      }
  } else {
    unsigned short* dst = vt + (size_t)b * CH * NT;
#pragma unroll
    for (int mi = 0; mi < 4; ++mi)
#pragma unroll
      for (int ni = 0; ni < 4; ++ni) {
        int col = colbase + ni * 16 + (lane & 15);
        float bb = bias[col];
        int row0 = rowbase + mi * 16 + ((lane >> 4) << 2);
        ushort4v pk;
#pragma unroll
        for (int r = 0; r < 4; ++r) pk[r] = f2bf(acc[mi][ni][r] + bb);
        *(ushort4v*)(dst + (size_t)col * NT + row0) = pk;
      }
  }
}

// ---------------- flash attention: Q-tile 64 (16/wave), KV-tile 64, D=256 ----------------
__global__ __launch_bounds__(256) void attn_kernel(
    const unsigned short* __restrict__ q, const unsigned short* __restrict__ k,
    const unsigned short* __restrict__ vt, unsigned short* __restrict__ oa) {
  __shared__ char Ks[32768];   // [64 rows][256 ch] bf16, XOR-swizzled
  __shared__ char Vs[32768];   // [256 ch][64 kv] bf16, XOR-swizzled
  __shared__ char Ps[9216];    // per-wave [16][72] bf16
  int tid = threadIdx.x, lane = tid & 63, wid = tid >> 6;
  int b = blockIdx.y;
  int q0 = blockIdx.x * 64;
  const unsigned short* qb = q + (size_t)b * NT * CH;
  const unsigned short* kb = k + (size_t)b * NT * CH;
  const unsigned short* vb = vt + (size_t)b * CH * NT;

  // Q fragments in registers (16 rows x 256)
  short8 qf[8];
  int qrow = q0 + wid * 16 + (lane & 15);
#pragma unroll
  for (int ks = 0; ks < 8; ++ks)
    qf[ks] = *(const short8*)(qb + (size_t)qrow * CH + ks * 32 + ((lane >> 4) << 3));

  f32x4 zero4 = {0.f, 0.f, 0.f, 0.f};
  f32x4 o[16];
#pragma unroll
  for (int ci = 0; ci < 16; ++ci) o[ci] = zero4;
  float mrun[4], lrun[4];
#pragma unroll
  for (int r = 0; r < 4; ++r) { mrun[r] = -INFINITY; lrun[r] = 0.f; }

  unsigned short* psw = (unsigned short*)(Ps + wid * 2304);

  for (int t = 0; t < 36; ++t) {
    int kt0 = t * 64;
#pragma unroll
    for (int it = 0; it < 8; ++it) {
      int li = it * 256 + tid;
      int X = li * 16;
      {
        int row = X >> 9;
        int colb = (X & 511) ^ ((row & 7) << 4);
        gload_lds16((const char*)kb + ((size_t)(kt0 + row) * CH) * 2 + colb,
                    Ks + it * 4096 + wid * 1024);
      }
      {
        int row = X >> 7;
        int colb = (X & 127) ^ ((row & 7) << 4);
        gload_lds16((const char*)vb + ((size_t)row * NT + kt0) * 2 + colb,
                    Vs + it * 4096 + wid * 1024);
      }
    }
    __syncthreads();

    // S = Q K^T  (16 q-rows x 64 kv-cols per wave)
    f32x4 s[4];
#pragma unroll
    for (int ct = 0; ct < 4; ++ct) s[ct] = zero4;
#pragma unroll
    for (int ct = 0; ct < 4; ++ct) {
      int row = ct * 16 + (lane & 15);
#pragma unroll
      for (int ks = 0; ks < 8; ++ks) {
        int cb = ks * 64 + ((lane >> 4) << 4);
        short8 kf = *(const short8*)(Ks + row * 512 + (cb ^ ((row & 7) << 4)));
        s[ct] = __builtin_amdgcn_mfma_f32_16x16x32_bf16(qf[ks], kf, s[ct], 0, 0, 0);
      }
    }
#pragma unroll
    for (int ct = 0; ct < 4; ++ct) s[ct] *= ATTN_SCALE;

    // online softmax (rows live in 4-lane-replicated groups; reduce over 16 lanes)
    float mnew[4], alpha[4];
#pragma unroll
    for (int r = 0; r < 4; ++r) {
      float v = fmaxf(fmaxf(s[0][r], s[1][r]), fmaxf(s[2][r], s[3][r]));
#pragma unroll
      for (int off = 1; off < 16; off <<= 1) v = fmaxf(v, __shfl_xor(v, off));
      mnew[r] = fmaxf(mrun[r], v);
      alpha[r] = __expf(mrun[r] - mnew[r]);
      mrun[r] = mnew[r];
    }
    float rowsum[4] = {0.f, 0.f, 0.f, 0.f};
#pragma unroll
    for (int ct = 0; ct < 4; ++ct) {
#pragma unroll
      for (int r = 0; r < 4; ++r) {
        float p = __expf(s[ct][r] - mnew[r]);
        psw[(((lane >> 4) << 2) + r) * 72 + ct * 16 + (lane & 15)] = f2bf(p);
        rowsum[r] += p;
      }
    }
#pragma unroll
    for (int r = 0; r < 4; ++r) {
      float v = rowsum[r];
#pragma unroll
      for (int off = 1; off < 16; off <<= 1) v += __shfl_xor(v, off);
      lrun[r] = lrun[r] * alpha[r] + v;
    }
#pragma unroll
    for (int ci = 0; ci < 16; ++ci) {
      f32x4 t4 = o[ci];
#pragma unroll
      for (int r = 0; r < 4; ++r) t4[r] *= alpha[r];
      o[ci] = t4;
    }

    // O += P V   (P via per-wave LDS re-fragmentation; V^T tiles: contiguous K)
#pragma unroll
    for (int ks2 = 0; ks2 < 2; ++ks2) {
      short8 pa = *(const short8*)(Ps + wid * 2304 + (lane & 15) * 144 +
                                   ks2 * 64 + ((lane >> 4) << 4));
#pragma unroll
      for (int ci = 0; ci < 16; ++ci) {
        int row = ci * 16 + (lane & 15);
        int cb = ks2 * 64 + ((lane >> 4) << 4);
        short8 vf = *(const short8*)(Vs + row * 128 + (cb ^ ((row & 7) << 4)));
        o[ci] = __builtin_amdgcn_mfma_f32_16x16x32_bf16(pa, vf, o[ci], 0, 0, 0);
      }
    }
    __syncthreads();
  }

  unsigned short* ob = oa + (size_t)b * NT * CH;
#pragma unroll
  for (int r = 0; r < 4; ++r) lrun[r] = 1.f / lrun[r];
#pragma unroll
  for (int ci = 0; ci < 16; ++ci) {
    int col = ci * 16 + (lane & 15);
#pragma unroll
    for (int r = 0; r < 4; ++r) {
      int row = q0 + wid * 16 + ((lane >> 4) << 2) + r;
      ob[(size_t)row * CH + col] = f2bf(o[ci][r] * lrun[r]);
    }
  }
}

// ---------------- output projection + bias + residual, out [B,C,N] fp32 ----------------
__global__ __launch_bounds__(256) void oproj_kernel(
    const unsigned short* __restrict__ oa, const unsigned short* __restrict__ wp,
    const float* __restrict__ bp, const float* __restrict__ x1,
    float* __restrict__ outp) {
  __shared__ char As[16384];
  __shared__ char Bs[16384];
  int tid = threadIdx.x;
  int lane = tid & 63, wid = tid >> 6;
  int b = blockIdx.z;
  const unsigned short* A = oa + (size_t)b * NT * CH;
  int m0 = blockIdx.x * 128;
  int c0 = blockIdx.y * 128;
  int wr = wid >> 1, wc = wid & 1;

  f32x4 zero4 = {0.f, 0.f, 0.f, 0.f};
  f32x4 acc[4][4];
#pragma unroll
  for (int i = 0; i < 4; ++i)
#pragma unroll
    for (int j = 0; j < 4; ++j) acc[i][j] = zero4;

  for (int kt = 0; kt < 4; ++kt) {
#pragma unroll
    for (int it = 0; it < 4; ++it) {
      int li = it * 256 + tid;
      int X = li * 16;
      int row = X >> 7;
      int colb = (X & 127) ^ ((row & 7) << 4);
      gload_lds16((const char*)A + ((size_t)(m0 + row) * CH + kt * 64) * 2 + colb,
                  As + it * 4096 + wid * 1024);
      gload_lds16((const char*)wp + ((size_t)(c0 + row) * CH + kt * 64) * 2 + colb,
                  Bs + it * 4096 + wid * 1024);
    }
    __syncthreads();
#pragma unroll
    for (int kk = 0; kk < 2; ++kk) {
      int cb = kk * 64 + ((lane >> 4) << 4);
      short8 af[4], bf[4];
#pragma unroll
      for (int mi = 0; mi < 4; ++mi) {
        int row = wr * 64 + mi * 16 + (lane & 15);
        af[mi] = *(const short8*)(As + row * 128 + (cb ^ ((row & 7) << 4)));
      }
#pragma unroll
      for (int ni = 0; ni < 4; ++ni) {
        int row = wc * 64 + ni * 16 + (lane & 15);
        bf[ni] = *(const short8*)(Bs + row * 128 + (cb ^ ((row & 7) << 4)));
      }
#pragma unroll
      for (int mi = 0; mi < 4; ++mi)
#pragma unroll
        for (int ni = 0; ni < 4; ++ni)
          acc[mi][ni] = __builtin_amdgcn_mfma_f32_16x16x32_bf16(
              af[mi], bf[ni], acc[mi][ni], 0, 0, 0);
    }
    __syncthreads();
  }

  int colbase = c0 + wc * 64;
  int rowbase = m0 + wr * 64;
#pragma unroll
  for (int mi = 0; mi < 4; ++mi)
#pragma unroll
    for (int ni = 0; ni < 4; ++ni) {
      int col = colbase + ni * 16 + (lane & 15);
      float bb = bp[col];
      int row0 = rowbase + mi * 16 + ((lane >> 4) << 2);
      int base = (b * CH + col) * NT + row0;
      float4v xv = *(const float4v*)(x1 + base);
      float4v rs;
#pragma unroll
      for (int r = 0; r < 4; ++r) rs[r] = acc[mi][ni][r] + bb + xv[r];
      *(float4v*)(outp + base) = rs;
    }
}

extern "C" void kernel_launch(void* const* d_in, const int* in_sizes, int n_in,
                              void* d_out, int out_size, void* d_ws, size_t ws_size,
                              hipStream_t stream) {
  (void)in_sizes; (void)n_in; (void)out_size; (void)ws_size;
  const float* x1 = (const float*)d_in[0];
  const float* x2 = (const float*)d_in[1];
  const float* Wq = (const float*)d_in[2];
  const float* bq = (const float*)d_in[3];
  const float* Wk = (const float*)d_in[4];
  const float* bk = (const float*)d_in[5];
  const float* Wv = (const float*)d_in[6];
  const float* bv = (const float*)d_in[7];
  const float* Wp = (const float*)d_in[8];
  const float* bp = (const float*)d_in[9];
  const float* wnq = (const float*)d_in[10];
  const float* bnq = (const float*)d_in[11];
  const float* wnkv = (const float*)d_in[12];
  const float* bnkv = (const float*)d_in[13];
  float* outp = (float*)d_out;

  const size_t TSZ = (size_t)NB * NT * CH;  // 4718592 elements
  unsigned short* xq = (unsigned short*)d_ws;
  unsigned short* xkv = xq + TSZ;
  unsigned short* qb = xkv + TSZ;
  unsigned short* kbuf = qb + TSZ;
  unsigned short* vtb = kbuf + TSZ;
  unsigned short* oab = vtb + TSZ;
  unsigned short* wbf = oab + TSZ;  // 4 x 65536

  wconv_kernel<<<dim3(64, 4), dim3(256), 0, stream>>>(Wq, Wk, Wv, Wp, wbf);
  ln_kernel<<<dim3(9, 8), dim3(256), 0, stream>>>(x1, wnq, bnq, xq);
  ln_kernel<<<dim3(9, 8), dim3(256), 0, stream>>>(x2, wnkv, bnkv, xkv);
  proj_kernel<<<dim3(18, 2, 24), dim3(256), 0, stream>>>(xq, xkv, wbf, bq, bk, bv,
                                                         qb, kbuf, vtb);
  attn_kernel<<<dim3(36, 8), dim3(256), 0, stream>>>(qb, kbuf, vtb, oab);
  oproj_kernel<<<dim3(18, 2, 8), dim3(256), 0, stream>>>(oab, wbf + 3 * 65536, bp,
                                                         x1, outp);
}

// Round 2
// 202.222 us; speedup vs baseline: 1.6127x; 1.6127x over previous
//
#include <hip/hip_runtime.h>

#define NB 8
#define CH 256
#define NT 2304
#define KVSPLIT 2
#define TILES_PER_SPLIT 18
#define ATTN_SCALE 0.17677669529663687f
#define LN_EPS 1e-6f

typedef __attribute__((ext_vector_type(8))) short short8;
typedef __attribute__((ext_vector_type(4))) float f32x4;
typedef __attribute__((ext_vector_type(4))) unsigned short ushort4v;
typedef __attribute__((ext_vector_type(8))) unsigned short ushort8v;
typedef __attribute__((ext_vector_type(4))) float float4v;

__device__ __forceinline__ unsigned short f2bf(float f) {
  unsigned int u = __float_as_uint(f);
  u += 0x7fffu + ((u >> 16) & 1u);
  return (unsigned short)(u >> 16);
}
__device__ __forceinline__ float bf2f(unsigned short s) {
  return __uint_as_float(((unsigned int)s) << 16);
}

__device__ __forceinline__ void gload_lds16(const void* g, void* l) {
  __builtin_amdgcn_global_load_lds(
      (const __attribute__((address_space(1))) unsigned int*)g,
      (__attribute__((address_space(3))) unsigned int*)l, 16, 0, 0);
}

// ---------------- weight fp32 -> bf16 convert ----------------
__global__ __launch_bounds__(256) void wconv_kernel(
    const float* __restrict__ wq, const float* __restrict__ wk,
    const float* __restrict__ wv, const float* __restrict__ wp,
    unsigned short* __restrict__ out) {
  int z = blockIdx.y;
  const float* src = (z == 0) ? wq : (z == 1) ? wk : (z == 2) ? wv : wp;
  unsigned short* dst = out + z * 65536;
  int i = (blockIdx.x * 256 + threadIdx.x) * 4;
  float4v v = *(const float4v*)(src + i);
  ushort4v r;
  r[0] = f2bf(v[0]); r[1] = f2bf(v[1]); r[2] = f2bf(v[2]); r[3] = f2bf(v[3]);
  *(ushort4v*)(dst + i) = r;
}

// ---------------- channel LayerNorm + transpose to [B,N,C] bf16 ----------------
// 64 tokens/block, 4 waves split the channel range; LDS cross-wave stat reduce.
__global__ __launch_bounds__(256) void ln_kernel(
    const float* __restrict__ x, const float* __restrict__ w,
    const float* __restrict__ bias, unsigned short* __restrict__ out) {
  __shared__ float part[4][64][2];
  __shared__ float fin[64][2];
  int tid = threadIdx.x;
  int lane = tid & 63, wv = tid >> 6;
  int n0 = blockIdx.x * 64;
  int b = blockIdx.y;
  const float* xp = x + (size_t)b * CH * NT + n0 + lane;
  float sum = 0.f, ss = 0.f;
#pragma unroll 4
  for (int c = wv * 64; c < wv * 64 + 64; ++c) {
    float v = xp[(size_t)c * NT];
    sum += v; ss += v * v;
  }
  part[wv][lane][0] = sum;
  part[wv][lane][1] = ss;
  __syncthreads();
  if (tid < 64) {
    float s = 0.f, q = 0.f;
#pragma unroll
    for (int wi = 0; wi < 4; ++wi) { s += part[wi][tid][0]; q += part[wi][tid][1]; }
    float u = s * (1.0f / CH);
    float var = q * (1.0f / CH) - u * u;
    fin[tid][0] = u;
    fin[tid][1] = rsqrtf(var + LN_EPS);
  }
  __syncthreads();
  float u = fin[lane][0], rstd = fin[lane][1];
  unsigned short* op = out + ((size_t)b * NT + n0 + lane) * CH;
  for (int c0 = wv * 64; c0 < wv * 64 + 64; c0 += 8) {
    ushort8v pk;
#pragma unroll
    for (int j = 0; j < 8; ++j) {
      float v = xp[(size_t)(c0 + j) * NT];
      pk[j] = f2bf((v - u) * rstd * w[c0 + j] + bias[c0 + j]);
    }
    *(ushort8v*)(op + c0) = pk;
  }
}

// ---------------- QKV projection GEMM (128x128, BK=64, 4 waves) ----------------
__global__ __launch_bounds__(256) void proj_kernel(
    const unsigned short* __restrict__ xq, const unsigned short* __restrict__ xkv,
    const unsigned short* __restrict__ wbf,
    const float* __restrict__ bq, const float* __restrict__ bk,
    const float* __restrict__ bv,
    unsigned short* __restrict__ q, unsigned short* __restrict__ k,
    unsigned short* __restrict__ vt) {
  __shared__ char As[16384];
  __shared__ char Bs[16384];
  int tid = threadIdx.x;
  int lane = tid & 63, wid = tid >> 6;
  int z = blockIdx.z;
  int b = z / 3, pz = z - b * 3;
  const unsigned short* A = ((pz == 0) ? xq : xkv) + (size_t)b * NT * CH;
  const unsigned short* W = wbf + pz * 65536;
  const float* bias = (pz == 0) ? bq : (pz == 1) ? bk : bv;
  int m0 = blockIdx.x * 128;
  int c0 = blockIdx.y * 128;
  int wr = wid >> 1, wc = wid & 1;

  f32x4 zero4 = {0.f, 0.f, 0.f, 0.f};
  f32x4 acc[4][4];
#pragma unroll
  for (int i = 0; i < 4; ++i)
#pragma unroll
    for (int j = 0; j < 4; ++j) acc[i][j] = zero4;

  for (int kt = 0; kt < 4; ++kt) {
#pragma unroll
    for (int it = 0; it < 4; ++it) {
      int li = it * 256 + tid;
      int X = li * 16;
      int row = X >> 7;
      int colb = (X & 127) ^ ((row & 7) << 4);
      gload_lds16((const char*)A + ((size_t)(m0 + row) * CH + kt * 64) * 2 + colb,
                  As + it * 4096 + wid * 1024);
      gload_lds16((const char*)W + ((size_t)(c0 + row) * CH + kt * 64) * 2 + colb,
                  Bs + it * 4096 + wid * 1024);
    }
    __syncthreads();
#pragma unroll
    for (int kk = 0; kk < 2; ++kk) {
      int cb = kk * 64 + ((lane >> 4) << 4);
      short8 af[4], bf[4];
#pragma unroll
      for (int mi = 0; mi < 4; ++mi) {
        int row = wr * 64 + mi * 16 + (lane & 15);
        af[mi] = *(const short8*)(As + row * 128 + (cb ^ ((row & 7) << 4)));
      }
#pragma unroll
      for (int ni = 0; ni < 4; ++ni) {
        int row = wc * 64 + ni * 16 + (lane & 15);
        bf[ni] = *(const short8*)(Bs + row * 128 + (cb ^ ((row & 7) << 4)));
      }
#pragma unroll
      for (int mi = 0; mi < 4; ++mi)
#pragma unroll
        for (int ni = 0; ni < 4; ++ni)
          acc[mi][ni] = __builtin_amdgcn_mfma_f32_16x16x32_bf16(
              af[mi], bf[ni], acc[mi][ni], 0, 0, 0);
    }
    __syncthreads();
  }

  int colbase = c0 + wc * 64;
  int rowbase = m0 + wr * 64;
  if (pz < 2) {
    unsigned short* dst = ((pz == 0) ? q : k) + (size_t)b * NT * CH;
#pragma unroll
    for (int mi = 0; mi < 4; ++mi)
#pragma unroll
      for (int ni = 0; ni < 4; ++ni) {
        int col = colbase + ni * 16 + (lane & 15);
        float bb = bias[col];
        int row0 = rowbase + mi * 16 + ((lane >> 4) << 2);
#pragma unroll
        for (int r = 0; r < 4; ++r)
          dst[(size_t)(row0 + r) * CH + col] = f2bf(acc[mi][ni][r] + bb);
      }
  } else {
    unsigned short* dst = vt + (size_t)b * CH * NT;
#pragma unroll
    for (int mi = 0; mi < 4; ++mi)
#pragma unroll
      for (int ni = 0; ni < 4; ++ni) {
        int col = colbase + ni * 16 + (lane & 15);
        float bb = bias[col];
        int row0 = rowbase + mi * 16 + ((lane >> 4) << 2);
        ushort4v pk;
#pragma unroll
        for (int r = 0; r < 4; ++r) pk[r] = f2bf(acc[mi][ni][r] + bb);
        *(ushort4v*)(dst + (size_t)col * NT + row0) = pk;
      }
  }
}

// ---------------- flash attention with KV-split + PV wave-specialization ----
// Block: Q-tile 64 (16 q-rows per wave for QK^T), KV-tile 64.
// PV: wave w computes O[all 64 q][d in w*64..w*64+64) via block-wide P in LDS.
// Outputs unnormalized O (bf16) + per-row (m,l) partials per split.
__global__ __launch_bounds__(256, 2) void attn_kernel(
    const unsigned short* __restrict__ q, const unsigned short* __restrict__ k,
    const unsigned short* __restrict__ vt,
    unsigned short* __restrict__ opart, float* __restrict__ ml) {
  __shared__ char Ks[32768];   // [64 kv][256 ch] bf16, XOR-swizzled
  __shared__ char Vs[32768];   // [256 ch][64 kv] bf16, XOR-swizzled
  __shared__ char Ps[9216];    // [64 q][72 kv] bf16 (block-wide)
  __shared__ float Alf[64];    // per-row alpha for this tile
  int tid = threadIdx.x, lane = tid & 63, wid = tid >> 6;
  int b = blockIdx.z;
  int split = blockIdx.y;
  int q0 = blockIdx.x * 64;
  const unsigned short* qb = q + (size_t)b * NT * CH;
  const unsigned short* kb = k + (size_t)b * NT * CH;
  const unsigned short* vb = vt + (size_t)b * CH * NT;

  // Q fragments in registers (16 rows x 256 per wave)
  short8 qf[8];
  int qrow = q0 + wid * 16 + (lane & 15);
#pragma unroll
  for (int ks = 0; ks < 8; ++ks)
    qf[ks] = *(const short8*)(qb + (size_t)qrow * CH + ks * 32 + ((lane >> 4) << 3));

  f32x4 zero4 = {0.f, 0.f, 0.f, 0.f};
  f32x4 o[16];  // [qg][di]: O[qg*16 q-rows][wid*64 + di*16 d-cols]
#pragma unroll
  for (int ci = 0; ci < 16; ++ci) o[ci] = zero4;
  float mrun[4], lrun[4];
#pragma unroll
  for (int r = 0; r < 4; ++r) { mrun[r] = -INFINITY; lrun[r] = 0.f; }

  for (int t = 0; t < TILES_PER_SPLIT; ++t) {
    int kt0 = (split * TILES_PER_SPLIT + t) * 64;
#pragma unroll
    for (int it = 0; it < 8; ++it) {
      int li = it * 256 + tid;
      int X = li * 16;
      {
        int row = X >> 9;
        int colb = (X & 511) ^ ((row & 7) << 4);
        gload_lds16((const char*)kb + ((size_t)(kt0 + row) * CH) * 2 + colb,
                    Ks + it * 4096 + wid * 1024);
      }
      {
        int row = X >> 7;
        int colb = (X & 127) ^ ((row & 7) << 4);
        gload_lds16((const char*)vb + ((size_t)row * NT + kt0) * 2 + colb,
                    Vs + it * 4096 + wid * 1024);
      }
    }
    __syncthreads();

    // S = Q K^T  (16 q-rows x 64 kv per wave)
    f32x4 s[4];
#pragma unroll
    for (int ct = 0; ct < 4; ++ct) s[ct] = zero4;
#pragma unroll
    for (int ct = 0; ct < 4; ++ct) {
      int row = ct * 16 + (lane & 15);
#pragma unroll
      for (int ks = 0; ks < 8; ++ks) {
        int cb = ks * 64 + ((lane >> 4) << 4);
        short8 kf = *(const short8*)(Ks + row * 512 + (cb ^ ((row & 7) << 4)));
        s[ct] = __builtin_amdgcn_mfma_f32_16x16x32_bf16(qf[ks], kf, s[ct], 0, 0, 0);
      }
    }
#pragma unroll
    for (int ct = 0; ct < 4; ++ct) s[ct] *= ATTN_SCALE;

    // online softmax (row r of this lane = wid*16 + (lane>>4)*4 + r)
    float mnew[4], alpha[4];
#pragma unroll
    for (int r = 0; r < 4; ++r) {
      float v = fmaxf(fmaxf(s[0][r], s[1][r]), fmaxf(s[2][r], s[3][r]));
#pragma unroll
      for (int off = 1; off < 16; off <<= 1) v = fmaxf(v, __shfl_xor(v, off));
      mnew[r] = fmaxf(mrun[r], v);
      alpha[r] = __expf(mrun[r] - mnew[r]);
      mrun[r] = mnew[r];
    }
    float rowsum[4] = {0.f, 0.f, 0.f, 0.f};
    unsigned short* psw = (unsigned short*)Ps;
#pragma unroll
    for (int ct = 0; ct < 4; ++ct) {
#pragma unroll
      for (int r = 0; r < 4; ++r) {
        float p = __expf(s[ct][r] - mnew[r]);
        psw[(wid * 16 + ((lane >> 4) << 2) + r) * 72 + ct * 16 + (lane & 15)] =
            f2bf(p);
        rowsum[r] += p;
      }
    }
#pragma unroll
    for (int r = 0; r < 4; ++r) {
      if ((lane & 15) == r) Alf[wid * 16 + ((lane >> 4) << 2) + r] = alpha[r];
      float v = rowsum[r];
#pragma unroll
      for (int off = 1; off < 16; off <<= 1) v += __shfl_xor(v, off);
      lrun[r] = lrun[r] * alpha[r] + v;
    }
    __syncthreads();

    // rescale O by per-row alpha (all 64 rows, own d-range)
    f32x4 af[4];
#pragma unroll
    for (int qg = 0; qg < 4; ++qg)
      af[qg] = *(const f32x4*)(Alf + qg * 16 + ((lane >> 4) << 2));
#pragma unroll
    for (int qg = 0; qg < 4; ++qg)
#pragma unroll
      for (int di = 0; di < 4; ++di) o[qg * 4 + di] *= af[qg];

    // O += P V  (wave owns d-range wid*64..wid*64+64)
#pragma unroll
    for (int ks2 = 0; ks2 < 2; ++ks2) {
      short8 pa[4];
#pragma unroll
      for (int qg = 0; qg < 4; ++qg)
        pa[qg] = *(const short8*)(Ps + (qg * 16 + (lane & 15)) * 144 + ks2 * 64 +
                                  ((lane >> 4) << 4));
#pragma unroll
      for (int di = 0; di < 4; ++di) {
        int row = wid * 64 + di * 16 + (lane & 15);
        int cb = ks2 * 64 + ((lane >> 4) << 4);
        short8 vf = *(const short8*)(Vs + row * 128 + (cb ^ ((row & 7) << 4)));
#pragma unroll
        for (int qg = 0; qg < 4; ++qg)
          o[qg * 4 + di] = __builtin_amdgcn_mfma_f32_16x16x32_bf16(
              pa[qg], vf, o[qg * 4 + di], 0, 0, 0);
      }
    }
    __syncthreads();
  }

  // store unnormalized partial O (bf16) and (m,l)
  unsigned short* od = opart + ((size_t)(split * NB + b) * NT + q0) * CH;
#pragma unroll
  for (int qg = 0; qg < 4; ++qg)
#pragma unroll
    for (int di = 0; di < 4; ++di) {
      int d = wid * 64 + di * 16 + (lane & 15);
#pragma unroll
      for (int r = 0; r < 4; ++r) {
        int qr = qg * 16 + ((lane >> 4) << 2) + r;
        od[(size_t)qr * CH + d] = f2bf(o[qg * 4 + di][r]);
      }
    }
  float* mlp = ml + ((size_t)(split * NB + b) * NT + q0) * 2;
#pragma unroll
  for (int r = 0; r < 4; ++r) {
    if ((lane & 15) == r) {
      int qr = wid * 16 + ((lane >> 4) << 2) + r;
      mlp[qr * 2] = mrun[r];
      mlp[qr * 2 + 1] = lrun[r];
    }
  }
}

// ---------------- combine KV-split partials -> oa bf16 [B,N,C] --------------
__global__ __launch_bounds__(256) void combine_kernel(
    const unsigned short* __restrict__ opart, const float* __restrict__ ml,
    unsigned short* __restrict__ oa) {
  int g = blockIdx.x;  // 0..NB*NT-1
  int d = threadIdx.x;
  float m0 = ml[(size_t)g * 2], l0 = ml[(size_t)g * 2 + 1];
  float m1 = ml[((size_t)NB * NT + g) * 2], l1 = ml[((size_t)NB * NT + g) * 2 + 1];
  float M = fmaxf(m0, m1);
  float w0 = __expf(m0 - M), w1 = __expf(m1 - M);
  float L = w0 * l0 + w1 * l1;
  float o0 = bf2f(opart[(size_t)g * CH + d]);
  float o1 = bf2f(opart[((size_t)NB * NT + g) * CH + d]);
  oa[(size_t)g * CH + d] = f2bf((w0 * o0 + w1 * o1) / L);
}

// ---------------- output projection + bias + residual, out [B,C,N] fp32 ----------------
__global__ __launch_bounds__(256) void oproj_kernel(
    const unsigned short* __restrict__ oa, const unsigned short* __restrict__ wp,
    const float* __restrict__ bp, const float* __restrict__ x1,
    float* __restrict__ outp) {
  __shared__ char As[16384];
  __shared__ char Bs[16384];
  int tid = threadIdx.x;
  int lane = tid & 63, wid = tid >> 6;
  int b = blockIdx.z;
  const unsigned short* A = oa + (size_t)b * NT * CH;
  int m0 = blockIdx.x * 128;
  int c0 = blockIdx.y * 128;
  int wr = wid >> 1, wc = wid & 1;

  f32x4 zero4 = {0.f, 0.f, 0.f, 0.f};
  f32x4 acc[4][4];
#pragma unroll
  for (int i = 0; i < 4; ++i)
#pragma unroll
    for (int j = 0; j < 4; ++j) acc[i][j] = zero4;

  for (int kt = 0; kt < 4; ++kt) {
#pragma unroll
    for (int it = 0; it < 4; ++it) {
      int li = it * 256 + tid;
      int X = li * 16;
      int row = X >> 7;
      int colb = (X & 127) ^ ((row & 7) << 4);
      gload_lds16((const char*)A + ((size_t)(m0 + row) * CH + kt * 64) * 2 + colb,
                  As + it * 4096 + wid * 1024);
      gload_lds16((const char*)wp + ((size_t)(c0 + row) * CH + kt * 64) * 2 + colb,
                  Bs + it * 4096 + wid * 1024);
    }
    __syncthreads();
#pragma unroll
    for (int kk = 0; kk < 2; ++kk) {
      int cb = kk * 64 + ((lane >> 4) << 4);
      short8 af[4], bf[4];
#pragma unroll
      for (int mi = 0; mi < 4; ++mi) {
        int row = wr * 64 + mi * 16 + (lane & 15);
        af[mi] = *(const short8*)(As + row * 128 + (cb ^ ((row & 7) << 4)));
      }
#pragma unroll
      for (int ni = 0; ni < 4; ++ni) {
        int row = wc * 64 + ni * 16 + (lane & 15);
        bf[ni] = *(const short8*)(Bs + row * 128 + (cb ^ ((row & 7) << 4)));
      }
#pragma unroll
      for (int mi = 0; mi < 4; ++mi)
#pragma unroll
        for (int ni = 0; ni < 4; ++ni)
          acc[mi][ni] = __builtin_amdgcn_mfma_f32_16x16x32_bf16(
              af[mi], bf[ni], acc[mi][ni], 0, 0, 0);
    }
    __syncthreads();
  }

  int colbase = c0 + wc * 64;
  int rowbase = m0 + wr * 64;
#pragma unroll
  for (int mi = 0; mi < 4; ++mi)
#pragma unroll
    for (int ni = 0; ni < 4; ++ni) {
      int col = colbase + ni * 16 + (lane & 15);
      float bb = bp[col];
      int row0 = rowbase + mi * 16 + ((lane >> 4) << 2);
      int base = (b * CH + col) * NT + row0;
      float4v xv = *(const float4v*)(x1 + base);
      float4v rs;
#pragma unroll
      for (int r = 0; r < 4; ++r) rs[r] = acc[mi][ni][r] + bb + xv[r];
      *(float4v*)(outp + base) = rs;
    }
}

extern "C" void kernel_launch(void* const* d_in, const int* in_sizes, int n_in,
                              void* d_out, int out_size, void* d_ws, size_t ws_size,
                              hipStream_t stream) {
  (void)in_sizes; (void)n_in; (void)out_size; (void)ws_size;
  const float* x1 = (const float*)d_in[0];
  const float* x2 = (const float*)d_in[1];
  const float* Wq = (const float*)d_in[2];
  const float* bq = (const float*)d_in[3];
  const float* Wk = (const float*)d_in[4];
  const float* bk = (const float*)d_in[5];
  const float* Wv = (const float*)d_in[6];
  const float* bv = (const float*)d_in[7];
  const float* Wp = (const float*)d_in[8];
  const float* bp = (const float*)d_in[9];
  const float* wnq = (const float*)d_in[10];
  const float* bnq = (const float*)d_in[11];
  const float* wnkv = (const float*)d_in[12];
  const float* bnkv = (const float*)d_in[13];
  float* outp = (float*)d_out;

  const size_t TSZ = (size_t)NB * NT * CH;  // 4718592 elements
  unsigned short* xq = (unsigned short*)d_ws;   // also opart (2*TSZ) after proj
  unsigned short* xkv = xq + TSZ;
  unsigned short* qb = xkv + TSZ;
  unsigned short* kbuf = qb + TSZ;
  unsigned short* vtb = kbuf + TSZ;
  unsigned short* oab = vtb + TSZ;
  unsigned short* wbf = oab + TSZ;              // 4 x 65536
  float* ml = (float*)(wbf + 4 * 65536);        // KVSPLIT * NB * NT * 2 floats
  unsigned short* opart = xq;                   // reuse: dead after proj

  wconv_kernel<<<dim3(64, 4), dim3(256), 0, stream>>>(Wq, Wk, Wv, Wp, wbf);
  ln_kernel<<<dim3(36, 8), dim3(256), 0, stream>>>(x1, wnq, bnq, xq);
  ln_kernel<<<dim3(36, 8), dim3(256), 0, stream>>>(x2, wnkv, bnkv, xkv);
  proj_kernel<<<dim3(18, 2, 24), dim3(256), 0, stream>>>(xq, xkv, wbf, bq, bk, bv,
                                                         qb, kbuf, vtb);
  attn_kernel<<<dim3(36, KVSPLIT, 8), dim3(256), 0, stream>>>(qb, kbuf, vtb,
                                                              opart, ml);
  combine_kernel<<<dim3(NB * NT), dim3(256), 0, stream>>>(opart, ml, oab);
  oproj_kernel<<<dim3(18, 2, 8), dim3(256), 0, stream>>>(oab, wbf + 3 * 65536, bp,
                                                         x1, outp);
}

// Round 3
// 158.427 us; speedup vs baseline: 2.0585x; 1.2764x over previous
//
#include <hip/hip_runtime.h>

#define NB 8
#define CH 256
#define NT 2304
#define KVSPLIT 3
#define TPS 12  // kv tiles of 64 per split
#define ATTN_SCALE 0.17677669529663687f
#define LN_EPS 1e-6f

typedef __attribute__((ext_vector_type(8))) short short8;
typedef __attribute__((ext_vector_type(4))) float f32x4;
typedef __attribute__((ext_vector_type(4))) unsigned short ushort4v;
typedef __attribute__((ext_vector_type(8))) unsigned short ushort8v;
typedef __attribute__((ext_vector_type(4))) float float4v;

__device__ __forceinline__ unsigned short f2bf(float f) {
  unsigned int u = __float_as_uint(f);
  u += 0x7fffu + ((u >> 16) & 1u);
  return (unsigned short)(u >> 16);
}
__device__ __forceinline__ float bf2f(unsigned short s) {
  return __uint_as_float(((unsigned int)s) << 16);
}

__device__ __forceinline__ void gload_lds16(const void* g, void* l) {
  __builtin_amdgcn_global_load_lds(
      (const __attribute__((address_space(1))) unsigned int*)g,
      (__attribute__((address_space(3))) unsigned int*)l, 16, 0, 0);
}

// ---------------- weight fp32 -> bf16 convert ----------------
__global__ __launch_bounds__(256) void wconv_kernel(
    const float* __restrict__ wq, const float* __restrict__ wk,
    const float* __restrict__ wv, const float* __restrict__ wp,
    unsigned short* __restrict__ out) {
  int z = blockIdx.y;
  const float* src = (z == 0) ? wq : (z == 1) ? wk : (z == 2) ? wv : wp;
  unsigned short* dst = out + z * 65536;
  int i = (blockIdx.x * 256 + threadIdx.x) * 4;
  float4v v = *(const float4v*)(src + i);
  ushort4v r;
  r[0] = f2bf(v[0]); r[1] = f2bf(v[1]); r[2] = f2bf(v[2]); r[3] = f2bf(v[3]);
  *(ushort4v*)(dst + i) = r;
}

// ---------------- channel LayerNorm + transpose to [B,N,C] bf16 (x1 & x2 fused) ----
__global__ __launch_bounds__(256) void ln_kernel(
    const float* __restrict__ x1, const float* __restrict__ x2,
    const float* __restrict__ w1, const float* __restrict__ b1,
    const float* __restrict__ w2, const float* __restrict__ b2,
    unsigned short* __restrict__ o1, unsigned short* __restrict__ o2) {
  __shared__ float part[4][64][2];
  __shared__ float fin[64][2];
  int z = blockIdx.z;
  const float* x = z ? x2 : x1;
  const float* w = z ? w2 : w1;
  const float* bias = z ? b2 : b1;
  unsigned short* out = z ? o2 : o1;
  int tid = threadIdx.x;
  int lane = tid & 63, wv = tid >> 6;
  int n0 = blockIdx.x * 64;
  int b = blockIdx.y;
  const float* xp = x + (size_t)b * CH * NT + n0 + lane;
  float sum = 0.f, ss = 0.f;
#pragma unroll 4
  for (int c = wv * 64; c < wv * 64 + 64; ++c) {
    float v = xp[(size_t)c * NT];
    sum += v; ss += v * v;
  }
  part[wv][lane][0] = sum;
  part[wv][lane][1] = ss;
  __syncthreads();
  if (tid < 64) {
    float s = 0.f, q = 0.f;
#pragma unroll
    for (int wi = 0; wi < 4; ++wi) { s += part[wi][tid][0]; q += part[wi][tid][1]; }
    float u = s * (1.0f / CH);
    float var = q * (1.0f / CH) - u * u;
    fin[tid][0] = u;
    fin[tid][1] = rsqrtf(var + LN_EPS);
  }
  __syncthreads();
  float u = fin[lane][0], rstd = fin[lane][1];
  unsigned short* op = out + ((size_t)b * NT + n0 + lane) * CH;
  for (int c0 = wv * 64; c0 < wv * 64 + 64; c0 += 8) {
    ushort8v pk;
#pragma unroll
    for (int j = 0; j < 8; ++j) {
      float v = xp[(size_t)(c0 + j) * NT];
      pk[j] = f2bf((v - u) * rstd * w[c0 + j] + bias[c0 + j]);
    }
    *(ushort8v*)(op + c0) = pk;
  }
}

// ---------------- QKV projection GEMM (128x128, BK=64, 4 waves) ----------------
__global__ __launch_bounds__(256) void proj_kernel(
    const unsigned short* __restrict__ xq, const unsigned short* __restrict__ xkv,
    const unsigned short* __restrict__ wbf,
    const float* __restrict__ bq, const float* __restrict__ bk,
    const float* __restrict__ bv,
    unsigned short* __restrict__ q, unsigned short* __restrict__ k,
    unsigned short* __restrict__ vt) {
  __shared__ char As[16384];
  __shared__ char Bs[16384];
  int tid = threadIdx.x;
  int lane = tid & 63, wid = tid >> 6;
  int z = blockIdx.z;
  int b = z / 3, pz = z - b * 3;
  const unsigned short* A = ((pz == 0) ? xq : xkv) + (size_t)b * NT * CH;
  const unsigned short* W = wbf + pz * 65536;
  const float* bias = (pz == 0) ? bq : (pz == 1) ? bk : bv;
  int m0 = blockIdx.x * 128;
  int c0 = blockIdx.y * 128;
  int wr = wid >> 1, wc = wid & 1;

  f32x4 zero4 = {0.f, 0.f, 0.f, 0.f};
  f32x4 acc[4][4];
#pragma unroll
  for (int i = 0; i < 4; ++i)
#pragma unroll
    for (int j = 0; j < 4; ++j) acc[i][j] = zero4;

  for (int kt = 0; kt < 4; ++kt) {
#pragma unroll
    for (int it = 0; it < 4; ++it) {
      int li = it * 256 + tid;
      int X = li * 16;
      int row = X >> 7;
      int colb = (X & 127) ^ ((row & 7) << 4);
      gload_lds16((const char*)A + ((size_t)(m0 + row) * CH + kt * 64) * 2 + colb,
                  As + it * 4096 + wid * 1024);
      gload_lds16((const char*)W + ((size_t)(c0 + row) * CH + kt * 64) * 2 + colb,
                  Bs + it * 4096 + wid * 1024);
    }
    __syncthreads();
#pragma unroll
    for (int kk = 0; kk < 2; ++kk) {
      int cb = kk * 64 + ((lane >> 4) << 4);
      short8 af[4], bf[4];
#pragma unroll
      for (int mi = 0; mi < 4; ++mi) {
        int row = wr * 64 + mi * 16 + (lane & 15);
        af[mi] = *(const short8*)(As + row * 128 + (cb ^ ((row & 7) << 4)));
      }
#pragma unroll
      for (int ni = 0; ni < 4; ++ni) {
        int row = wc * 64 + ni * 16 + (lane & 15);
        bf[ni] = *(const short8*)(Bs + row * 128 + (cb ^ ((row & 7) << 4)));
      }
#pragma unroll
      for (int mi = 0; mi < 4; ++mi)
#pragma unroll
        for (int ni = 0; ni < 4; ++ni)
          acc[mi][ni] = __builtin_amdgcn_mfma_f32_16x16x32_bf16(
              af[mi], bf[ni], acc[mi][ni], 0, 0, 0);
    }
    __syncthreads();
  }

  int colbase = c0 + wc * 64;
  int rowbase = m0 + wr * 64;
  if (pz < 2) {
    unsigned short* dst = ((pz == 0) ? q : k) + (size_t)b * NT * CH;
#pragma unroll
    for (int mi = 0; mi < 4; ++mi)
#pragma unroll
      for (int ni = 0; ni < 4; ++ni) {
        int col = colbase + ni * 16 + (lane & 15);
        float bb = bias[col];
        int row0 = rowbase + mi * 16 + ((lane >> 4) << 2);
#pragma unroll
        for (int r = 0; r < 4; ++r)
          dst[(size_t)(row0 + r) * CH + col] = f2bf(acc[mi][ni][r] + bb);
      }
  } else {
    unsigned short* dst = vt + (size_t)b * CH * NT;
#pragma unroll
    for (int mi = 0; mi < 4; ++mi)
#pragma unroll
      for (int ni = 0; ni < 4; ++ni) {
        int col = colbase + ni * 16 + (lane & 15);
        float bb = bias[col];
        int row0 = rowbase + mi * 16 + ((lane >> 4) << 2);
        ushort4v pk;
#pragma unroll
        for (int r = 0; r < 4; ++r) pk[r] = f2bf(acc[mi][ni][r] + bb);
        *(ushort4v*)(dst + (size_t)col * NT + row0) = pk;
      }
  }
}

// ---------------- flash attention v3 ----------------------------------------
// Swapped QK^T (S^T = K·Q): q = lane&15 -> in-lane softmax, b64 P-writes.
// V read direct from global (no reuse within block). K double-buffered in LDS.
__global__ __launch_bounds__(256, 2) void attn_kernel(
    const unsigned short* __restrict__ q, const unsigned short* __restrict__ k,
    const unsigned short* __restrict__ vt,
    unsigned short* __restrict__ op0, unsigned short* __restrict__ op1,
    unsigned short* __restrict__ op2, float* __restrict__ ml) {
  __shared__ char Ks[2][32768];  // [64 kv][256 ch] bf16, XOR-swizzled
  __shared__ char Ps[9216];      // [64 q][72 kv] bf16
  __shared__ float Alf[64];
  int tid = threadIdx.x, lane = tid & 63, wid = tid >> 6;
  int b = blockIdx.z;
  int split = blockIdx.y;
  int q0 = blockIdx.x * 64;
  const unsigned short* qb = q + (size_t)b * NT * CH;
  const unsigned short* kb = k + (size_t)b * NT * CH;
  const unsigned short* vb = vt + (size_t)b * CH * NT;
  int hi = lane >> 4, lo = lane & 15;

  // Q fragments (B-operand): 16 q-rows x 256 ch per wave
  short8 qf[8];
  int qrow = q0 + wid * 16 + lo;
#pragma unroll
  for (int ks = 0; ks < 8; ++ks)
    qf[ks] = *(const short8*)(qb + (size_t)qrow * CH + ks * 32 + hi * 8);

  f32x4 zero4 = {0.f, 0.f, 0.f, 0.f};
  f32x4 o[16];  // [qg][di]: O[qg*16+hi*4+r (q)][wid*64+di*16+lo (d)]
#pragma unroll
  for (int ci = 0; ci < 16; ++ci) o[ci] = zero4;
  float mrun = -INFINITY, lrun = 0.f;

  int kt0base = split * TPS * 64;
  // prologue: stage K tile 0 into buf 0
#pragma unroll
  for (int it = 0; it < 8; ++it) {
    int X = (it * 256 + tid) * 16;
    int row = X >> 9;
    int colb = (X & 511) ^ ((row & 7) << 4);
    gload_lds16((const char*)kb + ((size_t)(kt0base + row) * CH) * 2 + colb,
                Ks[0] + it * 4096 + wid * 1024);
  }
  __syncthreads();

  for (int t = 0; t < TPS; ++t) {
    int kt0 = kt0base + t * 64;
    int cur = t & 1;
    // stage next K tile into other buffer (overlaps QK^T + softmax)
    if (t + 1 < TPS) {
#pragma unroll
      for (int it = 0; it < 8; ++it) {
        int X = (it * 256 + tid) * 16;
        int row = X >> 9;
        int colb = (X & 511) ^ ((row & 7) << 4);
        gload_lds16((const char*)kb + ((size_t)(kt0 + 64 + row) * CH) * 2 + colb,
                    Ks[cur ^ 1] + it * 4096 + wid * 1024);
      }
    }
    // V fragments direct from global (consumed after barrier1)
    short8 vf[8];
#pragma unroll
    for (int di = 0; di < 4; ++di)
#pragma unroll
      for (int ks2 = 0; ks2 < 2; ++ks2)
        vf[di * 2 + ks2] = *(const short8*)(
            vb + (size_t)(wid * 64 + di * 16 + lo) * NT + kt0 + ks2 * 32 + hi * 8);

    // S^T = K Q  (rows = kv, cols = q): per lane 16 kv values for q = lo
    f32x4 s[4];
#pragma unroll
    for (int ct = 0; ct < 4; ++ct) s[ct] = zero4;
#pragma unroll
    for (int ct = 0; ct < 4; ++ct) {
      int row = ct * 16 + lo;
      const char* kp = Ks[cur] + row * 512;
      int swz = (row & 7) << 4;
#pragma unroll
      for (int ks = 0; ks < 8; ++ks) {
        short8 kf = *(const short8*)(kp + ((ks * 64 + hi * 16) ^ swz));
        s[ct] = __builtin_amdgcn_mfma_f32_16x16x32_bf16(kf, qf[ks], s[ct], 0, 0, 0);
      }
    }

    // in-lane online softmax over 16 kv (cross-hi via 2 shuffles)
    float mx = -INFINITY;
#pragma unroll
    for (int ct = 0; ct < 4; ++ct) {
      f32x4 sv = s[ct] * ATTN_SCALE;
      s[ct] = sv;
      mx = fmaxf(fmaxf(fmaxf(mx, sv[0]), fmaxf(sv[1], sv[2])), sv[3]);
    }
    mx = fmaxf(mx, __shfl_xor(mx, 16));
    mx = fmaxf(mx, __shfl_xor(mx, 32));
    float mnew = fmaxf(mrun, mx);
    float alpha = __expf(mrun - mnew);
    mrun = mnew;
    float rs = 0.f;
    unsigned short* prow = (unsigned short*)(Ps + (wid * 16 + lo) * 144 + hi * 8);
#pragma unroll
    for (int ct = 0; ct < 4; ++ct) {
      ushort4v pk;
#pragma unroll
      for (int r = 0; r < 4; ++r) {
        float p = __expf(s[ct][r] - mnew);
        rs += p;
        pk[r] = f2bf(p);
      }
      *(ushort4v*)(prow + ct * 16) = pk;  // kv = ct*16 + hi*4 .. +4
    }
    rs += __shfl_xor(rs, 16);
    rs += __shfl_xor(rs, 32);
    lrun = lrun * alpha + rs;
    if (lane < 16) Alf[wid * 16 + lane] = alpha;
    __syncthreads();  // P, Alf visible; stage + vf drained (compiler vmcnt)

    // rescale own O slice
    f32x4 af[4];
#pragma unroll
    for (int qg = 0; qg < 4; ++qg)
      af[qg] = *(const f32x4*)(Alf + qg * 16 + hi * 4);
#pragma unroll
    for (int qg = 0; qg < 4; ++qg)
#pragma unroll
      for (int di = 0; di < 4; ++di) o[qg * 4 + di] *= af[qg];

    // O += P V  (wave owns d-slice wid*64..+64)
#pragma unroll
    for (int ks2 = 0; ks2 < 2; ++ks2) {
      short8 pa[4];
#pragma unroll
      for (int qg = 0; qg < 4; ++qg)
        pa[qg] = *(const short8*)(Ps + (qg * 16 + lo) * 144 + ks2 * 64 + hi * 16);
#pragma unroll
      for (int di = 0; di < 4; ++di)
#pragma unroll
        for (int qg = 0; qg < 4; ++qg)
          o[qg * 4 + di] = __builtin_amdgcn_mfma_f32_16x16x32_bf16(
              pa[qg], vf[di * 2 + ks2], o[qg * 4 + di], 0, 0, 0);
    }
    __syncthreads();  // PV reads done before next P write / stage reuse
  }

  // store unnormalized partial O (bf16) and (m,l)
  unsigned short* od = ((split == 0) ? op0 : (split == 1) ? op1 : op2) +
                       ((size_t)b * NT + q0) * CH;
#pragma unroll
  for (int qg = 0; qg < 4; ++qg)
#pragma unroll
    for (int di = 0; di < 4; ++di) {
      int d = wid * 64 + di * 16 + lo;
#pragma unroll
      for (int r = 0; r < 4; ++r) {
        int qr = qg * 16 + hi * 4 + r;
        od[(size_t)qr * CH + d] = f2bf(o[qg * 4 + di][r]);
      }
    }
  float* mlp = ml + ((size_t)(split * NB + b) * NT + q0) * 2;
  if (lane < 16) {
    int qr = wid * 16 + lane;
    mlp[qr * 2] = mrun;
    mlp[qr * 2 + 1] = lrun;
  }
}

// ---------------- combine 3 KV-split partials -> oa bf16 [B,N,C] (in-place op2)
__global__ __launch_bounds__(256) void combine_kernel(
    const unsigned short* __restrict__ op0, const unsigned short* __restrict__ op1,
    const unsigned short* __restrict__ op2, const float* __restrict__ ml,
    unsigned short* __restrict__ oa) {
  int g = blockIdx.x;
  int d = threadIdx.x;
  const size_t S = (size_t)NB * NT;
  float m0 = ml[(size_t)g * 2], l0 = ml[(size_t)g * 2 + 1];
  float m1 = ml[(S + g) * 2], l1 = ml[(S + g) * 2 + 1];
  float m2 = ml[(2 * S + g) * 2], l2 = ml[(2 * S + g) * 2 + 1];
  float M = fmaxf(fmaxf(m0, m1), m2);
  float w0 = __expf(m0 - M), w1 = __expf(m1 - M), w2 = __expf(m2 - M);
  float L = w0 * l0 + w1 * l1 + w2 * l2;
  float o0 = bf2f(op0[(size_t)g * CH + d]);
  float o1 = bf2f(op1[(size_t)g * CH + d]);
  float o2 = bf2f(op2[(size_t)g * CH + d]);
  oa[(size_t)g * CH + d] = f2bf((w0 * o0 + w1 * o1 + w2 * o2) / L);
}

// ---------------- output projection + bias + residual, out [B,C,N] fp32 ----------------
__global__ __launch_bounds__(256) void oproj_kernel(
    const unsigned short* __restrict__ oa, const unsigned short* __restrict__ wp,
    const float* __restrict__ bp, const float* __restrict__ x1,
    float* __restrict__ outp) {
  __shared__ char As[16384];
  __shared__ char Bs[16384];
  int tid = threadIdx.x;
  int lane = tid & 63, wid = tid >> 6;
  int b = blockIdx.z;
  const unsigned short* A = oa + (size_t)b * NT * CH;
  int m0 = blockIdx.x * 128;
  int c0 = blockIdx.y * 128;
  int wr = wid >> 1, wc = wid & 1;

  f32x4 zero4 = {0.f, 0.f, 0.f, 0.f};
  f32x4 acc[4][4];
#pragma unroll
  for (int i = 0; i < 4; ++i)
#pragma unroll
    for (int j = 0; j < 4; ++j) acc[i][j] = zero4;

  for (int kt = 0; kt < 4; ++kt) {
#pragma unroll
    for (int it = 0; it < 4; ++it) {
      int li = it * 256 + tid;
      int X = li * 16;
      int row = X >> 7;
      int colb = (X & 127) ^ ((row & 7) << 4);
      gload_lds16((const char*)A + ((size_t)(m0 + row) * CH + kt * 64) * 2 + colb,
                  As + it * 4096 + wid * 1024);
      gload_lds16((const char*)wp + ((size_t)(c0 + row) * CH + kt * 64) * 2 + colb,
                  Bs + it * 4096 + wid * 1024);
    }
    __syncthreads();
#pragma unroll
    for (int kk = 0; kk < 2; ++kk) {
      int cb = kk * 64 + ((lane >> 4) << 4);
      short8 af[4], bf[4];
#pragma unroll
      for (int mi = 0; mi < 4; ++mi) {
        int row = wr * 64 + mi * 16 + (lane & 15);
        af[mi] = *(const short8*)(As + row * 128 + (cb ^ ((row & 7) << 4)));
      }
#pragma unroll
      for (int ni = 0; ni < 4; ++ni) {
        int row = wc * 64 + ni * 16 + (lane & 15);
        bf[ni] = *(const short8*)(Bs + row * 128 + (cb ^ ((row & 7) << 4)));
      }
#pragma unroll
      for (int mi = 0; mi < 4; ++mi)
#pragma unroll
        for (int ni = 0; ni < 4; ++ni)
          acc[mi][ni] = __builtin_amdgcn_mfma_f32_16x16x32_bf16(
              af[mi], bf[ni], acc[mi][ni], 0, 0, 0);
    }
    __syncthreads();
  }

  int colbase = c0 + wc * 64;
  int rowbase = m0 + wr * 64;
#pragma unroll
  for (int mi = 0; mi < 4; ++mi)
#pragma unroll
    for (int ni = 0; ni < 4; ++ni) {
      int col = colbase + ni * 16 + (lane & 15);
      float bb = bp[col];
      int row0 = rowbase + mi * 16 + ((lane >> 4) << 2);
      int base = (b * CH + col) * NT + row0;
      float4v xv = *(const float4v*)(x1 + base);
      float4v rs;
#pragma unroll
      for (int r = 0; r < 4; ++r) rs[r] = acc[mi][ni][r] + bb + xv[r];
      *(float4v*)(outp + base) = rs;
    }
}

extern "C" void kernel_launch(void* const* d_in, const int* in_sizes, int n_in,
                              void* d_out, int out_size, void* d_ws, size_t ws_size,
                              hipStream_t stream) {
  (void)in_sizes; (void)n_in; (void)out_size; (void)ws_size;
  const float* x1 = (const float*)d_in[0];
  const float* x2 = (const float*)d_in[1];
  const float* Wq = (const float*)d_in[2];
  const float* bq = (const float*)d_in[3];
  const float* Wk = (const float*)d_in[4];
  const float* bk = (const float*)d_in[5];
  const float* Wv = (const float*)d_in[6];
  const float* bv = (const float*)d_in[7];
  const float* Wp = (const float*)d_in[8];
  const float* bp = (const float*)d_in[9];
  const float* wnq = (const float*)d_in[10];
  const float* bnq = (const float*)d_in[11];
  const float* wnkv = (const float*)d_in[12];
  const float* bnkv = (const float*)d_in[13];
  float* outp = (float*)d_out;

  const size_t TSZ = (size_t)NB * NT * CH;  // 4718592 elements
  unsigned short* xq = (unsigned short*)d_ws;   // -> opart0 after proj
  unsigned short* xkv = xq + TSZ;               // -> opart1 after proj
  unsigned short* qb = xkv + TSZ;
  unsigned short* kbuf = qb + TSZ;
  unsigned short* vtb = kbuf + TSZ;
  unsigned short* oab = vtb + TSZ;              // opart2, combined in-place
  unsigned short* wbf = oab + TSZ;              // 4 x 65536
  float* ml = (float*)(wbf + 4 * 65536);        // KVSPLIT * NB * NT * 2 floats

  wconv_kernel<<<dim3(64, 4), dim3(256), 0, stream>>>(Wq, Wk, Wv, Wp, wbf);
  ln_kernel<<<dim3(36, 8, 2), dim3(256), 0, stream>>>(x1, x2, wnq, bnq, wnkv, bnkv,
                                                      xq, xkv);
  proj_kernel<<<dim3(18, 2, 24), dim3(256), 0, stream>>>(xq, xkv, wbf, bq, bk, bv,
                                                         qb, kbuf, vtb);
  attn_kernel<<<dim3(36, KVSPLIT, 8), dim3(256), 0, stream>>>(qb, kbuf, vtb,
                                                              xq, xkv, oab, ml);
  combine_kernel<<<dim3(NB * NT), dim3(256), 0, stream>>>(xq, xkv, oab, ml, oab);
  oproj_kernel<<<dim3(18, 2, 8), dim3(256), 0, stream>>>(oab, wbf + 3 * 65536, bp,
                                                         x1, outp);
}